// Round 3
// baseline (1005.684 us; speedup 1.0000x reference)
//
#include <hip/hip_runtime.h>

typedef _Float16 half8 __attribute__((ext_vector_type(8)));
typedef _Float16 half4v __attribute__((ext_vector_type(4)));
typedef float floatx4 __attribute__((ext_vector_type(4)));

#define B_ 32
#define L_ 1024
#define D_ 768

// Monotone float <-> uint key mapping (for atomicMax on floats incl. negatives).
__device__ __forceinline__ unsigned fkey(float f) {
    unsigned u = __float_as_uint(f);
    return (u & 0x80000000u) ? ~u : (u | 0x80000000u);
}
__device__ __forceinline__ float funkey(unsigned k) {
    return __uint_as_float((k & 0x80000000u) ? (k ^ 0x80000000u) : ~k);
}

__device__ __forceinline__ void gl2lds16(const _Float16* g, _Float16* s) {
    __builtin_amdgcn_global_load_lds(
        (const __attribute__((address_space(1))) void*)g,
        (__attribute__((address_space(3))) void*)s,
        16, 0, 0);
}

// ---------------------------------------------------------------------------
// Kernel A1: fp32 -> fp16 hi/lo row-major (streaming, 8 elems/thread),
// plus init of row/col max-key arrays. grid (12288, 2), block 256.
// ---------------------------------------------------------------------------
__global__ __launch_bounds__(256) void convert_rm(
    const float* __restrict__ X1, const float* __restrict__ X2,
    _Float16* __restrict__ X1h, _Float16* __restrict__ X1l,
    _Float16* __restrict__ X2h, _Float16* __restrict__ X2l,
    unsigned* __restrict__ rowMaxK, unsigned* __restrict__ colMaxK)
{
    const int inp = blockIdx.y;
    const float* __restrict__ X = inp ? X2 : X1;
    _Float16* __restrict__ Yh = inp ? X2h : X1h;
    _Float16* __restrict__ Yl = inp ? X2l : X1l;

    if (blockIdx.x < 128) {
        const int idx = blockIdx.x * 256 + threadIdx.x;   // 0..32767 = B*L
        (inp ? colMaxK : rowMaxK)[idx] = 0u;
    }

    const size_t base = ((size_t)blockIdx.x * 256 + threadIdx.x) * 8;
    const float4 x0 = *(const float4*)(X + base);
    const float4 x1 = *(const float4*)(X + base + 4);
    half8 hh, ll;
    hh[0] = (_Float16)x0.x; hh[1] = (_Float16)x0.y;
    hh[2] = (_Float16)x0.z; hh[3] = (_Float16)x0.w;
    hh[4] = (_Float16)x1.x; hh[5] = (_Float16)x1.y;
    hh[6] = (_Float16)x1.z; hh[7] = (_Float16)x1.w;
    ll[0] = (_Float16)(x0.x - (float)hh[0]); ll[1] = (_Float16)(x0.y - (float)hh[1]);
    ll[2] = (_Float16)(x0.z - (float)hh[2]); ll[3] = (_Float16)(x0.w - (float)hh[3]);
    ll[4] = (_Float16)(x1.x - (float)hh[4]); ll[5] = (_Float16)(x1.y - (float)hh[5]);
    ll[6] = (_Float16)(x1.z - (float)hh[6]); ll[7] = (_Float16)(x1.w - (float)hh[7]);
    *(half8*)(Yh + base) = hh;
    *(half8*)(Yl + base) = ll;
}

// ---------------------------------------------------------------------------
// Kernel A2: att = X1.X2^T from precomputed fp16 hi/lo via global_load_lds
// (m97 structure: linear LDS tiles [128][64], 2 barriers per k-step).
// 128x128 tile, BK=64, 256 threads / 4 waves (wave = 64x64 quadrant).
// 1-D grid 2048 with bijective XCD swizzle (nwg%8==0): 256 consecutive
// work-slots per XCD = 4 full batches -> operand panels stay in that L2.
// Epilogue: att write + row/col max atomics.
// ---------------------------------------------------------------------------
__global__ __launch_bounds__(256, 2) void gemm_att_h(
    const _Float16* __restrict__ X1h, const _Float16* __restrict__ X1l,
    const _Float16* __restrict__ X2h, const _Float16* __restrict__ X2l,
    float* __restrict__ att,
    unsigned* __restrict__ rowMaxK, unsigned* __restrict__ colMaxK)
{
    const int wg = blockIdx.x;                  // 0..2047
    const int widx = (wg & 7) * 256 + (wg >> 3);
    const int b  = widx >> 6;
    const int ij = widx & 63;
    const int i0 = (ij & 7) * 128, j0 = (ij >> 3) * 128;

    const int t = threadIdx.x;
    const int w = t >> 6, lane = t & 63, lr = lane & 15, kg = lane >> 4;
    const int wr = w & 1, wc = w >> 1;

    __shared__ __align__(16) _Float16 sAh[8192];   // [128][64] linear
    __shared__ __align__(16) _Float16 sAl[8192];
    __shared__ __align__(16) _Float16 sBh[8192];
    __shared__ __align__(16) _Float16 sBl[8192];

    const _Float16* __restrict__ Ah = X1h + ((size_t)b * L_ + i0) * D_;
    const _Float16* __restrict__ Al = X1l + ((size_t)b * L_ + i0) * D_;
    const _Float16* __restrict__ Bh = X2h + ((size_t)b * L_ + j0) * D_;
    const _Float16* __restrict__ Bl = X2l + ((size_t)b * L_ + j0) * D_;

    floatx4 acc[4][4];
    #pragma unroll
    for (int m = 0; m < 4; ++m)
        #pragma unroll
        for (int n = 0; n < 4; ++n) acc[m][n] = 0;

    for (int kt = 0; kt < D_; kt += 64) {
        __syncthreads();
        #pragma unroll
        for (int i = 0; i < 4; ++i) {
            const int v = t + 256 * i;
            const int row = v >> 3, c8 = v & 7;
            const size_t g = (size_t)row * D_ + kt + c8 * 8;
            gl2lds16(Ah + g, sAh + v * 8);
            gl2lds16(Al + g, sAl + v * 8);
            gl2lds16(Bh + g, sBh + v * 8);
            gl2lds16(Bl + g, sBl + v * 8);
        }
        __syncthreads();
        #pragma unroll
        for (int ks = 0; ks < 2; ++ks) {
            half8 aH[4], aL[4];
            #pragma unroll
            for (int m = 0; m < 4; ++m) {
                aH[m] = *(const half8*)(sAh + (wr * 64 + m * 16 + lr) * 64 + ks * 32 + kg * 8);
                aL[m] = *(const half8*)(sAl + (wr * 64 + m * 16 + lr) * 64 + ks * 32 + kg * 8);
            }
            #pragma unroll
            for (int n = 0; n < 4; ++n) {
                const half8 bH = *(const half8*)(sBh + (wc * 64 + n * 16 + lr) * 64 + ks * 32 + kg * 8);
                const half8 bL = *(const half8*)(sBl + (wc * 64 + n * 16 + lr) * 64 + ks * 32 + kg * 8);
                #pragma unroll
                for (int m = 0; m < 4; ++m) {
                    acc[m][n] = __builtin_amdgcn_mfma_f32_16x16x32_f16(aH[m], bH, acc[m][n], 0, 0, 0);
                    acc[m][n] = __builtin_amdgcn_mfma_f32_16x16x32_f16(aH[m], bL, acc[m][n], 0, 0, 0);
                    acc[m][n] = __builtin_amdgcn_mfma_f32_16x16x32_f16(aL[m], bH, acc[m][n], 0, 0, 0);
                }
            }
        }
    }

    // ---- write att tile (C layout: row = kg*4+r, col = lr) ----
    float* __restrict__ attB = att + (size_t)b * L_ * L_;
    #pragma unroll
    for (int m = 0; m < 4; ++m) {
        const int gi = i0 + wr * 64 + m * 16 + kg * 4;
        #pragma unroll
        for (int n = 0; n < 4; ++n) {
            const int gj = j0 + wc * 64 + n * 16 + lr;
            #pragma unroll
            for (int r = 0; r < 4; ++r)
                attB[(size_t)(gi + r) * L_ + gj] = acc[m][n][r];
        }
    }
    // ---- per-row maxes over this wave's 64-col slice ----
    #pragma unroll
    for (int m = 0; m < 4; ++m) {
        #pragma unroll
        for (int r = 0; r < 4; ++r) {
            float rm = fmaxf(fmaxf(acc[m][0][r], acc[m][1][r]),
                             fmaxf(acc[m][2][r], acc[m][3][r]));
            rm = fmaxf(rm, __shfl_xor(rm, 1));
            rm = fmaxf(rm, __shfl_xor(rm, 2));
            rm = fmaxf(rm, __shfl_xor(rm, 4));
            rm = fmaxf(rm, __shfl_xor(rm, 8));
            if (lr == 0)
                atomicMax(&rowMaxK[(size_t)b * L_ + i0 + wr * 64 + m * 16 + kg * 4 + r], fkey(rm));
        }
    }
    // ---- per-col maxes over this wave's 64-row slice ----
    #pragma unroll
    for (int n = 0; n < 4; ++n) {
        float cm = acc[0][n][0];
        #pragma unroll
        for (int m = 0; m < 4; ++m)
            #pragma unroll
            for (int r = 0; r < 4; ++r) cm = fmaxf(cm, acc[m][n][r]);
        cm = fmaxf(cm, __shfl_xor(cm, 16));
        cm = fmaxf(cm, __shfl_xor(cm, 32));
        if (kg == 0)
            atomicMax(&colMaxK[(size_t)b * L_ + j0 + wc * 64 + n * 16 + lr], fkey(cm));
    }
}

// ---------------------------------------------------------------------------
// Kernel A3: transpose fp16 hi row-major -> [b][d][l] (for PV V-operand).
// Writes into the (now dead) lo-array regions. grid (16, 12, 64), block 256.
// ---------------------------------------------------------------------------
__global__ __launch_bounds__(256) void convert_T(
    const _Float16* __restrict__ X1h, const _Float16* __restrict__ X2h,
    _Float16* __restrict__ X1hT, _Float16* __restrict__ X2hT)
{
    const int z = blockIdx.z;
    const int inp = z >> 5, b = z & 31;
    const _Float16* __restrict__ Xh = inp ? X2h : X1h;
    _Float16* __restrict__ YhT = inp ? X2hT : X1hT;

    const int l0 = blockIdx.x * 64, d0 = blockIdx.y * 64;
    const int t = threadIdx.x;

    __shared__ _Float16 sT[64 * 72];

    #pragma unroll
    for (int it = 0; it < 2; ++it) {
        const int row = (t >> 3) + it * 32, c8 = t & 7;
        *(half8*)(sT + row * 72 + c8 * 8) =
            *(const half8*)(Xh + ((size_t)b * L_ + l0 + row) * D_ + d0 + c8 * 8);
    }
    __syncthreads();
    #pragma unroll
    for (int it = 0; it < 2; ++it) {
        const int dr = (t >> 3) + it * 32, l8 = t & 7;
        half8 v;
        #pragma unroll
        for (int j = 0; j < 8; ++j) v[j] = sT[(l8 * 8 + j) * 72 + dr];
        *(half8*)(YhT + ((size_t)b * D_ + d0 + dr) * L_ + l0 + l8 * 8) = v;
    }
}

// ---------------------------------------------------------------------------
// Kernel 2 (v2): softmax (true max precomputed) + PV for both passes.
// 512-thread / 8-wave blocks, QB=32 q-rows, KB=64 keys/iter -> 2+ independent
// blocks co-resident per CU (the round-2 1024-thread version pinned at ONE
// block/CU -> zero cross-block overlap, 298 us latency-bound).
// Wave w owns d-cols [w*96, w*96+96) (6 col-tiles). V read direct from
// global (L2-resident), rotated in place so each fragment's reload for nt+1
// hides under >=20 MFMAs + P-phase + barrier. sP double-buffered -> 1
// barrier/key-tile. 1-D grid 2048 with bijective XCD swizzle (8 batches of
// one pass per XCD -> V stays in that XCD's L2).
// ---------------------------------------------------------------------------
__global__ __launch_bounds__(512, 4) void smpv2(
    const float* __restrict__ att,
    const _Float16* __restrict__ X1hT, const _Float16* __restrict__ X2hT,
    const unsigned* __restrict__ rowMaxK, const unsigned* __restrict__ colMaxK,
    float* __restrict__ out)
{
    const int wg = blockIdx.x;                   // 0..2047
    const int widx = (wg & 7) * 256 + (wg >> 3);
    const int pass = widx >> 10;
    const int b = (widx >> 5) & 31;
    const int r0 = (widx & 31) * 32;

    const _Float16* __restrict__ VTb = (pass ? X2hT : X1hT) + (size_t)b * D_ * L_;
    const float* __restrict__ attB = att + (size_t)b * L_ * L_;

    __shared__ __align__(16) _Float16 sPd[2 * 32 * 72];  // 9216 B (double P)
    __shared__ float sRed[32 * 64];                      // 8192 B (pass0 only)
    __shared__ float sL[32];

    const int t = threadIdx.x;
    const int w = t >> 6, lane = t & 63, lr = lane & 15, kg = lane >> 4;
    const int pr = t >> 4, pc = t & 15;          // pass1 P roles (pr 0..31)
    const int pr0 = t >> 3, pc0 = t & 7;         // pass0 P roles (pr0 0..63 keys)

    float mj4[4];
    float lp[4] = {0.f, 0.f, 0.f, 0.f};
    if (pass) {
        mj4[0] = funkey(rowMaxK[(size_t)b * L_ + r0 + pr]);
    } else {
        #pragma unroll
        for (int q = 0; q < 4; ++q)
            mj4[q] = funkey(colMaxK[(size_t)b * L_ + r0 + pc0 * 4 + q]);
    }

    floatx4 O[2][6];
    #pragma unroll
    for (int rg = 0; rg < 2; ++rg)
        #pragma unroll
        for (int ct = 0; ct < 6; ++ct) O[rg][ct] = 0;

    // att prefetch for nt=0
    float4 sreg;
    if (pass) sreg = *(const float4*)(attB + (size_t)(r0 + pr) * L_ + pc * 4);
    else      sreg = *(const float4*)(attB + (size_t)pr0 * L_ + r0 + pc0 * 4);

    // wave's V base: d = w*96 + ct*16 + lr, key = nt*64 + kh*32 + kg*8
    const _Float16* __restrict__ VTw = VTb + (size_t)(w * 96 + lr) * L_ + kg * 8;

    // V prologue: fragments for nt=0
    half8 vb0[6], vb1[6];
    #pragma unroll
    for (int ct = 0; ct < 6; ++ct) {
        const _Float16* __restrict__ p = VTw + (size_t)(ct * 16) * L_;
        vb0[ct] = *(const half8*)(p);
        vb1[ct] = *(const half8*)(p + 32);
    }

    for (int nt = 0; nt < 16; ++nt) {
        _Float16* __restrict__ sP = sPd + (nt & 1) * (32 * 72);

        // ---- P phase (uses prefetched att values) ----
        if (pass) {
            half4v hp;
            hp[0] = (_Float16)__expf(sreg.x - mj4[0]);
            hp[1] = (_Float16)__expf(sreg.y - mj4[0]);
            hp[2] = (_Float16)__expf(sreg.z - mj4[0]);
            hp[3] = (_Float16)__expf(sreg.w - mj4[0]);
            lp[0] += (float)hp[0] + (float)hp[1] + (float)hp[2] + (float)hp[3];
            *(half4v*)(sP + pr * 72 + pc * 4) = hp;
        } else {
            const _Float16 h0 = (_Float16)__expf(sreg.x - mj4[0]);
            const _Float16 h1 = (_Float16)__expf(sreg.y - mj4[1]);
            const _Float16 h2 = (_Float16)__expf(sreg.z - mj4[2]);
            const _Float16 h3 = (_Float16)__expf(sreg.w - mj4[3]);
            lp[0] += (float)h0; lp[1] += (float)h1;
            lp[2] += (float)h2; lp[3] += (float)h3;
            sP[(pc0 * 4 + 0) * 72 + pr0] = h0;
            sP[(pc0 * 4 + 1) * 72 + pr0] = h1;
            sP[(pc0 * 4 + 2) * 72 + pr0] = h2;
            sP[(pc0 * 4 + 3) * 72 + pr0] = h3;
        }
        __syncthreads();

        // att prefetch for nt+1 (drains at next barrier, fully hidden)
        if (nt < 15) {
            if (pass) sreg = *(const float4*)(attB + (size_t)(r0 + pr) * L_ + (nt + 1) * 64 + pc * 4);
            else      sreg = *(const float4*)(attB + (size_t)((nt + 1) * 64 + pr0) * L_ + r0 + pc0 * 4);
        }

        half8 aP[2][2];
        #pragma unroll
        for (int rg = 0; rg < 2; ++rg) {
            aP[rg][0] = *(const half8*)(sP + (rg * 16 + lr) * 72 + kg * 8);
            aP[rg][1] = *(const half8*)(sP + (rg * 16 + lr) * 72 + 32 + kg * 8);
        }

        #pragma unroll
        for (int ct = 0; ct < 6; ++ct) {
            O[0][ct] = __builtin_amdgcn_mfma_f32_16x16x32_f16(aP[0][0], vb0[ct], O[0][ct], 0, 0, 0);
            O[1][ct] = __builtin_amdgcn_mfma_f32_16x16x32_f16(aP[1][0], vb0[ct], O[1][ct], 0, 0, 0);
            O[0][ct] = __builtin_amdgcn_mfma_f32_16x16x32_f16(aP[0][1], vb1[ct], O[0][ct], 0, 0, 0);
            O[1][ct] = __builtin_amdgcn_mfma_f32_16x16x32_f16(aP[1][1], vb1[ct], O[1][ct], 0, 0, 0);
            // rotate-in V for nt+1 right after last use: latency hides under
            // the remaining MFMAs + next P phase + barrier.
            if (nt < 15) {
                const _Float16* __restrict__ p = VTw + (size_t)(ct * 16) * L_ + (nt + 1) * 64;
                vb0[ct] = *(const half8*)(p);
                vb1[ct] = *(const half8*)(p + 32);
            }
        }
    }

    // ---- denominators ----
    if (pass) {
        float lsum = lp[0];
        lsum += __shfl_xor(lsum, 1);
        lsum += __shfl_xor(lsum, 2);
        lsum += __shfl_xor(lsum, 4);
        lsum += __shfl_xor(lsum, 8);
        if (pc == 0) sL[pr] = lsum;
    } else {
        #pragma unroll
        for (int q = 0; q < 4; ++q) sRed[(pc0 * 4 + q) * 64 + pr0] = lp[q];
        __syncthreads();
        const int cl = t >> 4, i = t & 15;
        float s2 = 0.f;
        #pragma unroll
        for (int j = 0; j < 4; ++j) s2 += sRed[cl * 64 + i + 16 * j];
        s2 += __shfl_xor(s2, 1);
        s2 += __shfl_xor(s2, 2);
        s2 += __shfl_xor(s2, 4);
        s2 += __shfl_xor(s2, 8);
        if (i == 0) sL[cl] = s2;
    }
    __syncthreads();

    floatx4 linv[2];
    #pragma unroll
    for (int rg = 0; rg < 2; ++rg) {
        const floatx4 lv = *(const floatx4*)(sL + rg * 16 + kg * 4);
        #pragma unroll
        for (int r = 0; r < 4; ++r) linv[rg][r] = 1.0f / lv[r];
    }
    float* __restrict__ outB = out + (size_t)pass * B_ * L_ * D_ + ((size_t)b * L_ + r0) * D_;
    #pragma unroll
    for (int ct = 0; ct < 6; ++ct) {
        #pragma unroll
        for (int rg = 0; rg < 2; ++rg) {
            const floatx4 o = O[rg][ct] * linv[rg];
            const int gr = rg * 16 + kg * 4;
            const int d0 = w * 96 + ct * 16 + lr;
            #pragma unroll
            for (int r = 0; r < 4; ++r)
                outB[(size_t)(gr + r) * D_ + d0] = o[r];
        }
    }
}

// ---------------------------------------------------------------------------
// Mid-tier kernels (fp32-input GEMM path if ws only fits 2 fp16 arrays).
// ---------------------------------------------------------------------------
__global__ __launch_bounds__(256) void convert_kernel(
    const float* __restrict__ X1, const float* __restrict__ X2,
    _Float16* __restrict__ X1hT, _Float16* __restrict__ X2hT,
    unsigned* __restrict__ rowMaxK, unsigned* __restrict__ colMaxK)
{
    const int z = blockIdx.z;
    const int inp = z >> 5, b = z & 31;
    const float* __restrict__ X = inp ? X2 : X1;
    _Float16* __restrict__ YhT = inp ? X2hT : X1hT;

    const int l0 = blockIdx.x * 64, d0 = blockIdx.y * 64;
    const int t = threadIdx.x;

    if (blockIdx.y == 0 && t < 64)
        (inp ? colMaxK : rowMaxK)[(size_t)b * L_ + l0 + t] = 0u;

    __shared__ _Float16 sT[64 * 76];

    #pragma unroll
    for (int it = 0; it < 4; ++it) {
        const int row = (t >> 4) + it * 16;
        const int c4  = t & 15;
        const float4 x = *(const float4*)(X + ((size_t)b * L_ + l0 + row) * D_ + d0 + c4 * 4);
        half4v hh = {(_Float16)x.x, (_Float16)x.y, (_Float16)x.z, (_Float16)x.w};
        *(half4v*)(&sT[row * 76 + c4 * 4]) = hh;
    }
    __syncthreads();
    #pragma unroll
    for (int it = 0; it < 2; ++it) {
        const int dr = (t >> 3) + it * 32;
        const int l8 = t & 7;
        half8 v;
        #pragma unroll
        for (int j = 0; j < 8; ++j) v[j] = sT[(l8 * 8 + j) * 76 + dr];
        *(half8*)(YhT + ((size_t)b * D_ + d0 + dr) * L_ + l0 + l8 * 8) = v;
    }
}

#define KS0 72

__global__ __launch_bounds__(256, 2) void gemm_att(
    const float* __restrict__ X1, const float* __restrict__ X2,
    float* __restrict__ att,
    unsigned* __restrict__ rowMaxK, unsigned* __restrict__ colMaxK)
{
    const int b = blockIdx.z;
    const int i0 = blockIdx.x * 128, j0 = blockIdx.y * 128;
    const int t = threadIdx.x;
    const int w = t >> 6, lane = t & 63, lr = lane & 15, kg = lane >> 4;
    const int wr = w & 1, wc = w >> 1;

    const float* __restrict__ Ab = X1 + ((size_t)b * L_ + i0) * D_;
    const float* __restrict__ Bb = X2 + ((size_t)b * L_ + j0) * D_;

    __shared__ __align__(16) unsigned char smem[73728];
    _Float16* sAh = (_Float16*)smem;
    _Float16* sAl = (_Float16*)(smem + 18432);
    _Float16* sBh = (_Float16*)(smem + 36864);
    _Float16* sBl = (_Float16*)(smem + 55296);

    floatx4 acc[4][4];
    #pragma unroll
    for (int m = 0; m < 4; ++m)
        #pragma unroll
        for (int n = 0; n < 4; ++n) acc[m][n] = 0;

    for (int kt = 0; kt < D_; kt += 64) {
        __syncthreads();
        #pragma unroll
        for (int i = 0; i < 8; ++i) {
            const int v = t + 256 * i;
            const int row = v >> 4, c4 = v & 15;
            {
                const float4 x = *(const float4*)(Ab + (size_t)row * D_ + kt + c4 * 4);
                _Float16 h0 = (_Float16)x.x, h1 = (_Float16)x.y,
                         h2 = (_Float16)x.z, h3 = (_Float16)x.w;
                half4v hh = {h0, h1, h2, h3};
                half4v ll = {(_Float16)(x.x - (float)h0), (_Float16)(x.y - (float)h1),
                             (_Float16)(x.z - (float)h2), (_Float16)(x.w - (float)h3)};
                *(half4v*)(sAh + row * KS0 + c4 * 4) = hh;
                *(half4v*)(sAl + row * KS0 + c4 * 4) = ll;
            }
            {
                const float4 x = *(const float4*)(Bb + (size_t)row * D_ + kt + c4 * 4);
                _Float16 h0 = (_Float16)x.x, h1 = (_Float16)x.y,
                         h2 = (_Float16)x.z, h3 = (_Float16)x.w;
                half4v hh = {h0, h1, h2, h3};
                half4v ll = {(_Float16)(x.x - (float)h0), (_Float16)(x.y - (float)h1),
                             (_Float16)(x.z - (float)h2), (_Float16)(x.w - (float)h3)};
                *(half4v*)(sBh + row * KS0 + c4 * 4) = hh;
                *(half4v*)(sBl + row * KS0 + c4 * 4) = ll;
            }
        }
        __syncthreads();
        #pragma unroll
        for (int ks = 0; ks < 2; ++ks) {
            half8 aH[4], aL[4];
            #pragma unroll
            for (int m = 0; m < 4; ++m) {
                aH[m] = *(const half8*)(sAh + (wr * 64 + m * 16 + lr) * KS0 + ks * 32 + kg * 8);
                aL[m] = *(const half8*)(sAl + (wr * 64 + m * 16 + lr) * KS0 + ks * 32 + kg * 8);
            }
            #pragma unroll
            for (int n = 0; n < 4; ++n) {
                const half8 bH = *(const half8*)(sBh + (wc * 64 + n * 16 + lr) * KS0 + ks * 32 + kg * 8);
                const half8 bL = *(const half8*)(sBl + (wc * 64 + n * 16 + lr) * KS0 + ks * 32 + kg * 8);
                #pragma unroll
                for (int m = 0; m < 4; ++m) {
                    acc[m][n] = __builtin_amdgcn_mfma_f32_16x16x32_f16(aH[m], bH, acc[m][n], 0, 0, 0);
                    acc[m][n] = __builtin_amdgcn_mfma_f32_16x16x32_f16(aH[m], bL, acc[m][n], 0, 0, 0);
                    acc[m][n] = __builtin_amdgcn_mfma_f32_16x16x32_f16(aL[m], bH, acc[m][n], 0, 0, 0);
                }
            }
        }
    }

    float* __restrict__ attB = att + (size_t)b * L_ * L_;
    #pragma unroll
    for (int m = 0; m < 4; ++m) {
        const int gi = i0 + wr * 64 + m * 16 + kg * 4;
        #pragma unroll
        for (int n = 0; n < 4; ++n) {
            const int gj = j0 + wc * 64 + n * 16 + lr;
            #pragma unroll
            for (int r = 0; r < 4; ++r)
                attB[(size_t)(gi + r) * L_ + gj] = acc[m][n][r];
        }
    }
    #pragma unroll
    for (int m = 0; m < 4; ++m) {
        #pragma unroll
        for (int r = 0; r < 4; ++r) {
            float rm = fmaxf(fmaxf(acc[m][0][r], acc[m][1][r]),
                             fmaxf(acc[m][2][r], acc[m][3][r]));
            rm = fmaxf(rm, __shfl_xor(rm, 1));
            rm = fmaxf(rm, __shfl_xor(rm, 2));
            rm = fmaxf(rm, __shfl_xor(rm, 4));
            rm = fmaxf(rm, __shfl_xor(rm, 8));
            if (lr == 0)
                atomicMax(&rowMaxK[(size_t)b * L_ + i0 + wr * 64 + m * 16 + kg * 4 + r], fkey(rm));
        }
    }
    #pragma unroll
    for (int n = 0; n < 4; ++n) {
        float cm = acc[0][n][0];
        #pragma unroll
        for (int m = 0; m < 4; ++m)
            #pragma unroll
            for (int r = 0; r < 4; ++r) cm = fmaxf(cm, acc[m][n][r]);
        cm = fmaxf(cm, __shfl_xor(cm, 16));
        cm = fmaxf(cm, __shfl_xor(cm, 32));
        if (kg == 0)
            atomicMax(&colMaxK[(size_t)b * L_ + j0 + wc * 64 + n * 16 + lr], fkey(cm));
    }
}

// ---------------------------------------------------------------------------
// Fallback (fp32) if ws is too small for any staged path.
// ---------------------------------------------------------------------------
#define TQ 8
#define NTF 256
#define DC (D_ / 4)
#define QSTRIDE (D_ + 4)
#define SSTRIDE (L_ + 4)

__global__ __launch_bounds__(NTF) void attn_fused_fallback(
    const float* __restrict__ X1, const float* __restrict__ X2,
    float* __restrict__ out)
{
    const int pass = blockIdx.z;
    const int b    = blockIdx.y;
    const int r0   = blockIdx.x * TQ;

    const float* __restrict__ Qg = (pass ? X1 : X2) + ((size_t)b * L_ + r0) * D_;
    const float* __restrict__ Kg = (pass ? X2 : X1) + (size_t)b * L_ * D_;
    float* __restrict__ Og = out + (size_t)pass * B_ * L_ * D_
                                 + ((size_t)b * L_ + r0) * D_;

    __shared__ float sQ[TQ * QSTRIDE];
    __shared__ float sS2[TQ * SSTRIDE];

    const int t = threadIdx.x;

    for (int i = t; i < TQ * DC; i += NTF) {
        const int row = i / DC, c = i % DC;
        ((float4*)(sQ + row * QSTRIDE))[c] = ((const float4*)Qg)[i];
    }
    __syncthreads();

    {
        const int q  = t & (TQ - 1);
        const int kgI = t >> 3;
        float acc[32];
        #pragma unroll
        for (int w2 = 0; w2 < 32; ++w2) acc[w2] = 0.f;
        const float4* __restrict__ Qrow = (const float4*)(sQ + q * QSTRIDE);
        const float4* __restrict__ K4   = (const float4*)Kg;
        for (int c = 0; c < DC; ++c) {
            const float4 qv = Qrow[c];
            #pragma unroll
            for (int w2 = 0; w2 < 32; ++w2) {
                const float4 kv = K4[(kgI + 32 * w2) * DC + c];
                acc[w2] = fmaf(qv.x, kv.x, acc[w2]);
                acc[w2] = fmaf(qv.y, kv.y, acc[w2]);
                acc[w2] = fmaf(qv.z, kv.z, acc[w2]);
                acc[w2] = fmaf(qv.w, kv.w, acc[w2]);
            }
        }
        #pragma unroll
        for (int w2 = 0; w2 < 32; ++w2) sS2[q * SSTRIDE + kgI + 32 * w2] = acc[w2];
    }
    __syncthreads();

    {
        const int q = t >> 5;
        const int l = t & 31;
        float* __restrict__ row = sS2 + q * SSTRIDE;
        float mx = -3.0e38f;
        for (int k = l; k < L_; k += 32) mx = fmaxf(mx, row[k]);
        #pragma unroll
        for (int off = 16; off > 0; off >>= 1) mx = fmaxf(mx, __shfl_xor(mx, off));
        float se = 0.f;
        for (int k = l; k < L_; k += 32) {
            const float e = __expf(row[k] - mx);
            row[k] = e;
            se += e;
        }
        #pragma unroll
        for (int off = 16; off > 0; off >>= 1) se += __shfl_xor(se, off);
        const float inv = 1.0f / se;
        for (int k = l; k < L_; k += 32) row[k] *= inv;
    }
    __syncthreads();

    {
        const int q  = t & (TQ - 1);
        const int cg = t >> 3;
        float4 acc[6];
        #pragma unroll
        for (int r = 0; r < 6; ++r) acc[r] = make_float4(0.f, 0.f, 0.f, 0.f);
        const float* __restrict__ P   = sS2 + q * SSTRIDE;
        const float4* __restrict__ V4 = (const float4*)Kg;
        for (int k = 0; k < L_; ++k) {
            const float p = P[k];
            if (p > 1e-8f) {
                const float4* __restrict__ Vrow = V4 + (size_t)k * DC;
                #pragma unroll
                for (int r = 0; r < 6; ++r) {
                    const float4 v = Vrow[cg + 32 * r];
                    acc[r].x = fmaf(p, v.x, acc[r].x);
                    acc[r].y = fmaf(p, v.y, acc[r].y);
                    acc[r].z = fmaf(p, v.z, acc[r].z);
                    acc[r].w = fmaf(p, v.w, acc[r].w);
                }
            }
        }
        float4* __restrict__ O4 = (float4*)(Og + q * D_);
        #pragma unroll
        for (int r = 0; r < 6; ++r) O4[cg + 32 * r] = acc[r];
    }
}

extern "C" void kernel_launch(void* const* d_in, const int* in_sizes, int n_in,
                              void* d_out, int out_size, void* d_ws, size_t ws_size,
                              hipStream_t stream) {
    const float* X1 = (const float*)d_in[0];
    const float* X2 = (const float*)d_in[1];
    float* out = (float*)d_out;

    const size_t attBytes = (size_t)B_ * L_ * L_ * sizeof(float);     // 134,217,728
    const size_t hBytes   = (size_t)B_ * L_ * D_ * sizeof(_Float16);  // 50,331,648
    const size_t maxBytes = 2 * (size_t)B_ * L_ * sizeof(unsigned);   // 262,144
    const size_t needFull = attBytes + 4 * hBytes + maxBytes;         // ~320.25 MiB
    const size_t needMid  = attBytes + 2 * hBytes + maxBytes;         // ~224.25 MiB

    if (ws_size >= needFull) {
        float*    attW    = (float*)d_ws;
        _Float16* X1h     = (_Float16*)((char*)d_ws + attBytes);
        _Float16* X1l     = (_Float16*)((char*)d_ws + attBytes + 1 * hBytes);
        _Float16* X2h     = (_Float16*)((char*)d_ws + attBytes + 2 * hBytes);
        _Float16* X2l     = (_Float16*)((char*)d_ws + attBytes + 3 * hBytes);
        unsigned* rowMaxK = (unsigned*)((char*)d_ws + attBytes + 4 * hBytes);
        unsigned* colMaxK = rowMaxK + (size_t)B_ * L_;
        // transposed hi arrays overwrite the (then dead) lo arrays
        _Float16* X1hT = X1l;
        _Float16* X2hT = X2l;

        convert_rm<<<dim3(12288, 2), dim3(256), 0, stream>>>(
            X1, X2, X1h, X1l, X2h, X2l, rowMaxK, colMaxK);
        gemm_att_h<<<dim3(2048), dim3(256), 0, stream>>>(
            X1h, X1l, X2h, X2l, attW, rowMaxK, colMaxK);
        convert_T<<<dim3(L_ / 64, D_ / 64, B_ * 2), dim3(256), 0, stream>>>(
            X1h, X2h, X1hT, X2hT);
        smpv2<<<dim3(2048), dim3(512), 0, stream>>>(
            attW, X1hT, X2hT, rowMaxK, colMaxK, out);
    } else if (ws_size >= needMid) {
        float*    attW    = (float*)d_ws;
        _Float16* X1hT    = (_Float16*)((char*)d_ws + attBytes);
        _Float16* X2hT    = (_Float16*)((char*)d_ws + attBytes + hBytes);
        unsigned* rowMaxK = (unsigned*)((char*)d_ws + attBytes + 2 * hBytes);
        unsigned* colMaxK = rowMaxK + (size_t)B_ * L_;

        convert_kernel<<<dim3(L_ / 64, D_ / 64, B_ * 2), dim3(256), 0, stream>>>(
            X1, X2, X1hT, X2hT, rowMaxK, colMaxK);
        gemm_att<<<dim3(L_ / 128, L_ / 128, B_), dim3(256), 0, stream>>>(
            X1, X2, attW, rowMaxK, colMaxK);
        smpv2<<<dim3(2048), dim3(512), 0, stream>>>(
            attW, X1hT, X2hT, rowMaxK, colMaxK, out);
    } else {
        attn_fused_fallback<<<dim3(L_ / TQ, B_, 2), dim3(NTF), 0, stream>>>(X1, X2, out);
    }
}

// Round 4
// 806.302 us; speedup vs baseline: 1.2473x; 1.2473x over previous
//
#include <hip/hip_runtime.h>

typedef _Float16 half8 __attribute__((ext_vector_type(8)));
typedef _Float16 half4v __attribute__((ext_vector_type(4)));
typedef float floatx4 __attribute__((ext_vector_type(4)));

#define B_ 32
#define L_ 1024
#define D_ 768

// Monotone float <-> uint key mapping (for atomicMax on floats incl. negatives).
__device__ __forceinline__ unsigned fkey(float f) {
    unsigned u = __float_as_uint(f);
    return (u & 0x80000000u) ? ~u : (u | 0x80000000u);
}
__device__ __forceinline__ float funkey(unsigned k) {
    return __uint_as_float((k & 0x80000000u) ? (k ^ 0x80000000u) : ~k);
}

__device__ __forceinline__ void gl2lds16(const _Float16* g, _Float16* s) {
    __builtin_amdgcn_global_load_lds(
        (const __attribute__((address_space(1))) void*)g,
        (__attribute__((address_space(3))) void*)s,
        16, 0, 0);
}

// ---------------------------------------------------------------------------
// Kernel A1: fp32 -> fp16 hi/lo row-major (streaming, 8 elems/thread),
// plus init of row/col max-key arrays. grid (12288, 2), block 256.
// ---------------------------------------------------------------------------
__global__ __launch_bounds__(256) void convert_rm(
    const float* __restrict__ X1, const float* __restrict__ X2,
    _Float16* __restrict__ X1h, _Float16* __restrict__ X1l,
    _Float16* __restrict__ X2h, _Float16* __restrict__ X2l,
    unsigned* __restrict__ rowMaxK, unsigned* __restrict__ colMaxK)
{
    const int inp = blockIdx.y;
    const float* __restrict__ X = inp ? X2 : X1;
    _Float16* __restrict__ Yh = inp ? X2h : X1h;
    _Float16* __restrict__ Yl = inp ? X2l : X1l;

    if (blockIdx.x < 128) {
        const int idx = blockIdx.x * 256 + threadIdx.x;   // 0..32767 = B*L
        (inp ? colMaxK : rowMaxK)[idx] = 0u;
    }

    const size_t base = ((size_t)blockIdx.x * 256 + threadIdx.x) * 8;
    const float4 x0 = *(const float4*)(X + base);
    const float4 x1 = *(const float4*)(X + base + 4);
    half8 hh, ll;
    hh[0] = (_Float16)x0.x; hh[1] = (_Float16)x0.y;
    hh[2] = (_Float16)x0.z; hh[3] = (_Float16)x0.w;
    hh[4] = (_Float16)x1.x; hh[5] = (_Float16)x1.y;
    hh[6] = (_Float16)x1.z; hh[7] = (_Float16)x1.w;
    ll[0] = (_Float16)(x0.x - (float)hh[0]); ll[1] = (_Float16)(x0.y - (float)hh[1]);
    ll[2] = (_Float16)(x0.z - (float)hh[2]); ll[3] = (_Float16)(x0.w - (float)hh[3]);
    ll[4] = (_Float16)(x1.x - (float)hh[4]); ll[5] = (_Float16)(x1.y - (float)hh[5]);
    ll[6] = (_Float16)(x1.z - (float)hh[6]); ll[7] = (_Float16)(x1.w - (float)hh[7]);
    *(half8*)(Yh + base) = hh;
    *(half8*)(Yl + base) = ll;
}

// ---------------------------------------------------------------------------
// Kernel A2: att = X1.X2^T from precomputed fp16 hi/lo via global_load_lds
// (m97 structure: linear LDS tiles [128][64], 2 barriers per k-step).
// 128x128 tile, BK=64, 256 threads / 4 waves (wave = 64x64 quadrant).
// 1-D grid 2048 with bijective XCD swizzle. Epilogue: att + row/col max.
// ---------------------------------------------------------------------------
__global__ __launch_bounds__(256, 2) void gemm_att_h(
    const _Float16* __restrict__ X1h, const _Float16* __restrict__ X1l,
    const _Float16* __restrict__ X2h, const _Float16* __restrict__ X2l,
    float* __restrict__ att,
    unsigned* __restrict__ rowMaxK, unsigned* __restrict__ colMaxK)
{
    const int wg = blockIdx.x;                  // 0..2047
    const int widx = (wg & 7) * 256 + (wg >> 3);
    const int b  = widx >> 6;
    const int ij = widx & 63;
    const int i0 = (ij & 7) * 128, j0 = (ij >> 3) * 128;

    const int t = threadIdx.x;
    const int w = t >> 6, lane = t & 63, lr = lane & 15, kg = lane >> 4;
    const int wr = w & 1, wc = w >> 1;

    __shared__ __align__(16) _Float16 sAh[8192];   // [128][64] linear
    __shared__ __align__(16) _Float16 sAl[8192];
    __shared__ __align__(16) _Float16 sBh[8192];
    __shared__ __align__(16) _Float16 sBl[8192];

    const _Float16* __restrict__ Ah = X1h + ((size_t)b * L_ + i0) * D_;
    const _Float16* __restrict__ Al = X1l + ((size_t)b * L_ + i0) * D_;
    const _Float16* __restrict__ Bh = X2h + ((size_t)b * L_ + j0) * D_;
    const _Float16* __restrict__ Bl = X2l + ((size_t)b * L_ + j0) * D_;

    floatx4 acc[4][4];
    #pragma unroll
    for (int m = 0; m < 4; ++m)
        #pragma unroll
        for (int n = 0; n < 4; ++n) acc[m][n] = 0;

    for (int kt = 0; kt < D_; kt += 64) {
        __syncthreads();
        #pragma unroll
        for (int i = 0; i < 4; ++i) {
            const int v = t + 256 * i;
            const int row = v >> 3, c8 = v & 7;
            const size_t g = (size_t)row * D_ + kt + c8 * 8;
            gl2lds16(Ah + g, sAh + v * 8);
            gl2lds16(Al + g, sAl + v * 8);
            gl2lds16(Bh + g, sBh + v * 8);
            gl2lds16(Bl + g, sBl + v * 8);
        }
        __syncthreads();
        #pragma unroll
        for (int ks = 0; ks < 2; ++ks) {
            half8 aH[4], aL[4];
            #pragma unroll
            for (int m = 0; m < 4; ++m) {
                aH[m] = *(const half8*)(sAh + (wr * 64 + m * 16 + lr) * 64 + ks * 32 + kg * 8);
                aL[m] = *(const half8*)(sAl + (wr * 64 + m * 16 + lr) * 64 + ks * 32 + kg * 8);
            }
            #pragma unroll
            for (int n = 0; n < 4; ++n) {
                const half8 bH = *(const half8*)(sBh + (wc * 64 + n * 16 + lr) * 64 + ks * 32 + kg * 8);
                const half8 bL = *(const half8*)(sBl + (wc * 64 + n * 16 + lr) * 64 + ks * 32 + kg * 8);
                #pragma unroll
                for (int m = 0; m < 4; ++m) {
                    acc[m][n] = __builtin_amdgcn_mfma_f32_16x16x32_f16(aH[m], bH, acc[m][n], 0, 0, 0);
                    acc[m][n] = __builtin_amdgcn_mfma_f32_16x16x32_f16(aH[m], bL, acc[m][n], 0, 0, 0);
                    acc[m][n] = __builtin_amdgcn_mfma_f32_16x16x32_f16(aL[m], bH, acc[m][n], 0, 0, 0);
                }
            }
        }
    }

    float* __restrict__ attB = att + (size_t)b * L_ * L_;
    #pragma unroll
    for (int m = 0; m < 4; ++m) {
        const int gi = i0 + wr * 64 + m * 16 + kg * 4;
        #pragma unroll
        for (int n = 0; n < 4; ++n) {
            const int gj = j0 + wc * 64 + n * 16 + lr;
            #pragma unroll
            for (int r = 0; r < 4; ++r)
                attB[(size_t)(gi + r) * L_ + gj] = acc[m][n][r];
        }
    }
    #pragma unroll
    for (int m = 0; m < 4; ++m) {
        #pragma unroll
        for (int r = 0; r < 4; ++r) {
            float rm = fmaxf(fmaxf(acc[m][0][r], acc[m][1][r]),
                             fmaxf(acc[m][2][r], acc[m][3][r]));
            rm = fmaxf(rm, __shfl_xor(rm, 1));
            rm = fmaxf(rm, __shfl_xor(rm, 2));
            rm = fmaxf(rm, __shfl_xor(rm, 4));
            rm = fmaxf(rm, __shfl_xor(rm, 8));
            if (lr == 0)
                atomicMax(&rowMaxK[(size_t)b * L_ + i0 + wr * 64 + m * 16 + kg * 4 + r], fkey(rm));
        }
    }
    #pragma unroll
    for (int n = 0; n < 4; ++n) {
        float cm = acc[0][n][0];
        #pragma unroll
        for (int m = 0; m < 4; ++m)
            #pragma unroll
            for (int r = 0; r < 4; ++r) cm = fmaxf(cm, acc[m][n][r]);
        cm = fmaxf(cm, __shfl_xor(cm, 16));
        cm = fmaxf(cm, __shfl_xor(cm, 32));
        if (kg == 0)
            atomicMax(&colMaxK[(size_t)b * L_ + j0 + wc * 64 + n * 16 + lr], fkey(cm));
    }
}

// ---------------------------------------------------------------------------
// Kernel A3: transpose fp16 hi row-major -> [b][d][l] (PV V-operand).
// Writes into the (then dead) lo-array regions. grid (16, 12, 64), block 256.
// ---------------------------------------------------------------------------
__global__ __launch_bounds__(256) void convert_T(
    const _Float16* __restrict__ X1h, const _Float16* __restrict__ X2h,
    _Float16* __restrict__ X1hT, _Float16* __restrict__ X2hT)
{
    const int z = blockIdx.z;
    const int inp = z >> 5, b = z & 31;
    const _Float16* __restrict__ Xh = inp ? X2h : X1h;
    _Float16* __restrict__ YhT = inp ? X2hT : X1hT;

    const int l0 = blockIdx.x * 64, d0 = blockIdx.y * 64;
    const int t = threadIdx.x;

    __shared__ _Float16 sT[64 * 72];

    #pragma unroll
    for (int it = 0; it < 2; ++it) {
        const int row = (t >> 3) + it * 32, c8 = t & 7;
        *(half8*)(sT + row * 72 + c8 * 8) =
            *(const half8*)(Xh + ((size_t)b * L_ + l0 + row) * D_ + d0 + c8 * 8);
    }
    __syncthreads();
    #pragma unroll
    for (int it = 0; it < 2; ++it) {
        const int dr = (t >> 3) + it * 32, l8 = t & 7;
        half8 v;
        #pragma unroll
        for (int j = 0; j < 8; ++j) v[j] = sT[(l8 * 8 + j) * 72 + dr];
        *(half8*)(YhT + ((size_t)b * D_ + d0 + dr) * L_ + l0 + l8 * 8) = v;
    }
}

// ---------------------------------------------------------------------------
// Kernel 2 (v3): whole-row softmax P into LDS ONCE, then barrier-free PV GEMM.
//
// Round-3 post-mortem: per-key-tile __syncthreads() drains vmcnt(0) each nt,
// exposing a full load latency 16x per block; fixing prefetch around the
// barrier is futile. Here P (64 rows x 1024 keys fp16 = 129 KB swizzled LDS)
// is built in one pass over att (exp with precomputed true max), then the PV
// loop is a pure GEMM: sP read-only, V register-double-buffered from global
// (L2-resident via XCD swizzle), 12 MFMAs per k-step, NO barriers (2 total
// per block). Swizzle cb' = (cb + 2*(row&7)) & 127 spreads the ds_read_b128
// A-frag reads evenly over banks. grid 1024 (XCD-swizzled), block 1024,
// 1 block/CU (LDS-bound), 4 waves/SIMD.
// ---------------------------------------------------------------------------
#define PSTR 1032   // sP row stride in halves (1024 + 8): bank rotation +4/row

__global__ __launch_bounds__(1024) void smpv3(
    const float* __restrict__ att,
    const _Float16* __restrict__ X1hT, const _Float16* __restrict__ X2hT,
    const unsigned* __restrict__ rowMaxK, const unsigned* __restrict__ colMaxK,
    float* __restrict__ out)
{
    const int wg = blockIdx.x;                   // 0..1023
    const int widx = (wg & 7) * 128 + (wg >> 3); // bijective XCD swizzle
    const int pass = widx >> 9;
    const int b = (widx >> 4) & 31;
    const int r0 = (widx & 15) * 64;

    const _Float16* __restrict__ VTb = (pass ? X2hT : X1hT) + (size_t)b * D_ * L_;
    const float* __restrict__ attB = att + (size_t)b * L_ * L_;

    extern __shared__ __align__(16) unsigned char smem[];
    _Float16* sP  = (_Float16*)smem;                     // [64][PSTR] 132096 B
    float*    sRed = (float*)(smem + 64 * PSTR * 2);     // [64][16]   4096 B
    float*    sL  = (float*)(smem + 64 * PSTR * 2 + 4096); // [64]

    const int t = threadIdx.x;
    const int w = t >> 6, lane = t & 63, lr = lane & 15, kg = lane >> 4;

    // ---- phase 1: build P in LDS (swizzled), accumulate row-sum partials ----
    if (pass) {
        // row-softmax of att rows r0..r0+63 (row-major reads, float4)
        const int row = t >> 4, seg = t & 15;
        const float m = funkey(rowMaxK[(size_t)b * L_ + r0 + row]);
        const float* __restrict__ ar = attB + (size_t)(r0 + row) * L_;
        _Float16* __restrict__ sProw = sP + row * PSTR;
        const int sw = 2 * (row & 7);
        float psum = 0.f;
        #pragma unroll
        for (int g = 0; g < 16; ++g) {
            const int c = seg * 4 + g * 64;
            const float4 x = *(const float4*)(ar + c);
            half4v h;
            h[0] = (_Float16)__expf(x.x - m);
            h[1] = (_Float16)__expf(x.y - m);
            h[2] = (_Float16)__expf(x.z - m);
            h[3] = (_Float16)__expf(x.w - m);
            psum += (float)h[0] + (float)h[1] + (float)h[2] + (float)h[3];
            const int cb = ((c >> 3) + sw) & 127;
            *(half4v*)(sProw + cb * 8 + (c & 7)) = h;
        }
        sRed[row * 16 + seg] = psum;
    } else {
        // col-softmax: P0[j][i] = exp(att[i][r0+j] - colmax[j]).
        // lane = output row j -> att reads are 256 B wave-coalesced per key.
        const int j = t & 63, g16 = t >> 6;      // key chunk g16*64..+63
        const float m = funkey(colMaxK[(size_t)b * L_ + r0 + j]);
        _Float16* __restrict__ sProw = sP + j * PSTR;
        const int sw = 2 * (j & 7);
        const float* __restrict__ ac = attB + (size_t)(g16 * 64) * L_ + r0 + j;
        float psum = 0.f;
        #pragma unroll 4
        for (int kk = 0; kk < 64; ++kk) {
            const float x = ac[(size_t)kk * L_];
            const _Float16 e = (_Float16)__expf(x - m);
            psum += (float)e;
            const int k = g16 * 64 + kk;
            const int cb = ((k >> 3) + sw) & 127;
            sProw[cb * 8 + (k & 7)] = e;
        }
        sRed[j * 16 + g16] = psum;
    }
    __syncthreads();

    // ---- finalize row sums (wave-local shfl over 16-lane groups) ----
    {
        const int row = t >> 4, i = t & 15;
        float v = sRed[row * 16 + i];
        v += __shfl_xor(v, 1);
        v += __shfl_xor(v, 2);
        v += __shfl_xor(v, 4);
        v += __shfl_xor(v, 8);
        if (i == 0) sL[row] = v;
    }
    __syncthreads();

    // ---- phase 2: barrier-free PV GEMM. wave w owns d-cols w*48..w*48+47 ----
    floatx4 O[4][3];
    #pragma unroll
    for (int rg = 0; rg < 4; ++rg)
        #pragma unroll
        for (int ct = 0; ct < 3; ++ct) O[rg][ct] = 0;

    const _Float16* __restrict__ Vw = VTb + (size_t)(w * 48 + lr) * L_ + kg * 8;
    const int kgoff = kg + 2 * (lr & 7);

    half8 vA[3], vB[3], apA[4], apB[4];

    #pragma unroll
    for (int ct = 0; ct < 3; ++ct)
        vA[ct] = *(const half8*)(Vw + (size_t)(ct * 16) * L_);

    for (int ks = 0; ks < 32; ks += 2) {
        // prefetch ks+1 V
        #pragma unroll
        for (int ct = 0; ct < 3; ++ct)
            vB[ct] = *(const half8*)(Vw + (size_t)(ct * 16) * L_ + (ks + 1) * 32);
        // A-frags for ks
        {
            const int cb = (ks * 4 + kgoff) & 127;
            #pragma unroll
            for (int rg = 0; rg < 4; ++rg)
                apA[rg] = *(const half8*)(sP + (rg * 16 + lr) * PSTR + cb * 8);
        }
        #pragma unroll
        for (int rg = 0; rg < 4; ++rg)
            #pragma unroll
            for (int ct = 0; ct < 3; ++ct)
                O[rg][ct] = __builtin_amdgcn_mfma_f32_16x16x32_f16(apA[rg], vA[ct], O[rg][ct], 0, 0, 0);
        // prefetch ks+2 V (clamped redundant load at tail)
        {
            const int ksn = (ks + 2 < 32) ? ks + 2 : 31;
            #pragma unroll
            for (int ct = 0; ct < 3; ++ct)
                vA[ct] = *(const half8*)(Vw + (size_t)(ct * 16) * L_ + ksn * 32);
        }
        // A-frags for ks+1
        {
            const int cb = ((ks + 1) * 4 + kgoff) & 127;
            #pragma unroll
            for (int rg = 0; rg < 4; ++rg)
                apB[rg] = *(const half8*)(sP + (rg * 16 + lr) * PSTR + cb * 8);
        }
        #pragma unroll
        for (int rg = 0; rg < 4; ++rg)
            #pragma unroll
            for (int ct = 0; ct < 3; ++ct)
                O[rg][ct] = __builtin_amdgcn_mfma_f32_16x16x32_f16(apB[rg], vB[ct], O[rg][ct], 0, 0, 0);
    }

    // ---- epilogue: normalize and store ----
    floatx4 linv[4];
    #pragma unroll
    for (int rg = 0; rg < 4; ++rg) {
        const floatx4 lv = *(const floatx4*)(sL + rg * 16 + kg * 4);
        #pragma unroll
        for (int r = 0; r < 4; ++r) linv[rg][r] = 1.0f / lv[r];
    }
    float* __restrict__ outB = out + (size_t)pass * B_ * L_ * D_ + ((size_t)b * L_ + r0) * D_;
    #pragma unroll
    for (int rg = 0; rg < 4; ++rg) {
        #pragma unroll
        for (int ct = 0; ct < 3; ++ct) {
            const floatx4 o = O[rg][ct] * linv[rg];
            const int gr = rg * 16 + kg * 4;
            const int d0 = w * 48 + ct * 16 + lr;
            #pragma unroll
            for (int r = 0; r < 4; ++r)
                outB[(size_t)(gr + r) * D_ + d0] = o[r];
        }
    }
}

// ---------------------------------------------------------------------------
// Mid-tier kernels (fp32-input GEMM path if ws only fits 2 fp16 arrays).
// ---------------------------------------------------------------------------
__global__ __launch_bounds__(256) void convert_kernel(
    const float* __restrict__ X1, const float* __restrict__ X2,
    _Float16* __restrict__ X1hT, _Float16* __restrict__ X2hT,
    unsigned* __restrict__ rowMaxK, unsigned* __restrict__ colMaxK)
{
    const int z = blockIdx.z;
    const int inp = z >> 5, b = z & 31;
    const float* __restrict__ X = inp ? X2 : X1;
    _Float16* __restrict__ YhT = inp ? X2hT : X1hT;

    const int l0 = blockIdx.x * 64, d0 = blockIdx.y * 64;
    const int t = threadIdx.x;

    if (blockIdx.y == 0 && t < 64)
        (inp ? colMaxK : rowMaxK)[(size_t)b * L_ + l0 + t] = 0u;

    __shared__ _Float16 sT[64 * 76];

    #pragma unroll
    for (int it = 0; it < 4; ++it) {
        const int row = (t >> 4) + it * 16;
        const int c4  = t & 15;
        const float4 x = *(const float4*)(X + ((size_t)b * L_ + l0 + row) * D_ + d0 + c4 * 4);
        half4v hh = {(_Float16)x.x, (_Float16)x.y, (_Float16)x.z, (_Float16)x.w};
        *(half4v*)(&sT[row * 76 + c4 * 4]) = hh;
    }
    __syncthreads();
    #pragma unroll
    for (int it = 0; it < 2; ++it) {
        const int dr = (t >> 3) + it * 32;
        const int l8 = t & 7;
        half8 v;
        #pragma unroll
        for (int j = 0; j < 8; ++j) v[j] = sT[(l8 * 8 + j) * 76 + dr];
        *(half8*)(YhT + ((size_t)b * D_ + d0 + dr) * L_ + l0 + l8 * 8) = v;
    }
}

#define KS0 72

__global__ __launch_bounds__(256, 2) void gemm_att(
    const float* __restrict__ X1, const float* __restrict__ X2,
    float* __restrict__ att,
    unsigned* __restrict__ rowMaxK, unsigned* __restrict__ colMaxK)
{
    const int b = blockIdx.z;
    const int i0 = blockIdx.x * 128, j0 = blockIdx.y * 128;
    const int t = threadIdx.x;
    const int w = t >> 6, lane = t & 63, lr = lane & 15, kg = lane >> 4;
    const int wr = w & 1, wc = w >> 1;

    const float* __restrict__ Ab = X1 + ((size_t)b * L_ + i0) * D_;
    const float* __restrict__ Bb = X2 + ((size_t)b * L_ + j0) * D_;

    __shared__ __align__(16) unsigned char smemS[73728];
    _Float16* sAh = (_Float16*)smemS;
    _Float16* sAl = (_Float16*)(smemS + 18432);
    _Float16* sBh = (_Float16*)(smemS + 36864);
    _Float16* sBl = (_Float16*)(smemS + 55296);

    floatx4 acc[4][4];
    #pragma unroll
    for (int m = 0; m < 4; ++m)
        #pragma unroll
        for (int n = 0; n < 4; ++n) acc[m][n] = 0;

    for (int kt = 0; kt < D_; kt += 64) {
        __syncthreads();
        #pragma unroll
        for (int i = 0; i < 8; ++i) {
            const int v = t + 256 * i;
            const int row = v >> 4, c4 = v & 15;
            {
                const float4 x = *(const float4*)(Ab + (size_t)row * D_ + kt + c4 * 4);
                _Float16 h0 = (_Float16)x.x, h1 = (_Float16)x.y,
                         h2 = (_Float16)x.z, h3 = (_Float16)x.w;
                half4v hh = {h0, h1, h2, h3};
                half4v ll = {(_Float16)(x.x - (float)h0), (_Float16)(x.y - (float)h1),
                             (_Float16)(x.z - (float)h2), (_Float16)(x.w - (float)h3)};
                *(half4v*)(sAh + row * KS0 + c4 * 4) = hh;
                *(half4v*)(sAl + row * KS0 + c4 * 4) = ll;
            }
            {
                const float4 x = *(const float4*)(Bb + (size_t)row * D_ + kt + c4 * 4);
                _Float16 h0 = (_Float16)x.x, h1 = (_Float16)x.y,
                         h2 = (_Float16)x.z, h3 = (_Float16)x.w;
                half4v hh = {h0, h1, h2, h3};
                half4v ll = {(_Float16)(x.x - (float)h0), (_Float16)(x.y - (float)h1),
                             (_Float16)(x.z - (float)h2), (_Float16)(x.w - (float)h3)};
                *(half4v*)(sBh + row * KS0 + c4 * 4) = hh;
                *(half4v*)(sBl + row * KS0 + c4 * 4) = ll;
            }
        }
        __syncthreads();
        #pragma unroll
        for (int ks = 0; ks < 2; ++ks) {
            half8 aH[4], aL[4];
            #pragma unroll
            for (int m = 0; m < 4; ++m) {
                aH[m] = *(const half8*)(sAh + (wr * 64 + m * 16 + lr) * KS0 + ks * 32 + kg * 8);
                aL[m] = *(const half8*)(sAl + (wr * 64 + m * 16 + lr) * KS0 + ks * 32 + kg * 8);
            }
            #pragma unroll
            for (int n = 0; n < 4; ++n) {
                const half8 bH = *(const half8*)(sBh + (wc * 64 + n * 16 + lr) * KS0 + ks * 32 + kg * 8);
                const half8 bL = *(const half8*)(sBl + (wc * 64 + n * 16 + lr) * KS0 + ks * 32 + kg * 8);
                #pragma unroll
                for (int m = 0; m < 4; ++m) {
                    acc[m][n] = __builtin_amdgcn_mfma_f32_16x16x32_f16(aH[m], bH, acc[m][n], 0, 0, 0);
                    acc[m][n] = __builtin_amdgcn_mfma_f32_16x16x32_f16(aH[m], bL, acc[m][n], 0, 0, 0);
                    acc[m][n] = __builtin_amdgcn_mfma_f32_16x16x32_f16(aL[m], bH, acc[m][n], 0, 0, 0);
                }
            }
        }
    }

    float* __restrict__ attB = att + (size_t)b * L_ * L_;
    #pragma unroll
    for (int m = 0; m < 4; ++m) {
        const int gi = i0 + wr * 64 + m * 16 + kg * 4;
        #pragma unroll
        for (int n = 0; n < 4; ++n) {
            const int gj = j0 + wc * 64 + n * 16 + lr;
            #pragma unroll
            for (int r = 0; r < 4; ++r)
                attB[(size_t)(gi + r) * L_ + gj] = acc[m][n][r];
        }
    }
    #pragma unroll
    for (int m = 0; m < 4; ++m) {
        #pragma unroll
        for (int r = 0; r < 4; ++r) {
            float rm = fmaxf(fmaxf(acc[m][0][r], acc[m][1][r]),
                             fmaxf(acc[m][2][r], acc[m][3][r]));
            rm = fmaxf(rm, __shfl_xor(rm, 1));
            rm = fmaxf(rm, __shfl_xor(rm, 2));
            rm = fmaxf(rm, __shfl_xor(rm, 4));
            rm = fmaxf(rm, __shfl_xor(rm, 8));
            if (lr == 0)
                atomicMax(&rowMaxK[(size_t)b * L_ + i0 + wr * 64 + m * 16 + kg * 4 + r], fkey(rm));
        }
    }
    #pragma unroll
    for (int n = 0; n < 4; ++n) {
        float cm = acc[0][n][0];
        #pragma unroll
        for (int m = 0; m < 4; ++m)
            #pragma unroll
            for (int r = 0; r < 4; ++r) cm = fmaxf(cm, acc[m][n][r]);
        cm = fmaxf(cm, __shfl_xor(cm, 16));
        cm = fmaxf(cm, __shfl_xor(cm, 32));
        if (kg == 0)
            atomicMax(&colMaxK[(size_t)b * L_ + j0 + wc * 64 + n * 16 + lr], fkey(cm));
    }
}

// ---------------------------------------------------------------------------
// Fallback (fp32) if ws is too small for any staged path.
// ---------------------------------------------------------------------------
#define TQ 8
#define NTF 256
#define DC (D_ / 4)
#define QSTRIDE (D_ + 4)
#define SSTRIDE (L_ + 4)

__global__ __launch_bounds__(NTF) void attn_fused_fallback(
    const float* __restrict__ X1, const float* __restrict__ X2,
    float* __restrict__ out)
{
    const int pass = blockIdx.z;
    const int b    = blockIdx.y;
    const int r0   = blockIdx.x * TQ;

    const float* __restrict__ Qg = (pass ? X1 : X2) + ((size_t)b * L_ + r0) * D_;
    const float* __restrict__ Kg = (pass ? X2 : X1) + (size_t)b * L_ * D_;
    float* __restrict__ Og = out + (size_t)pass * B_ * L_ * D_
                                 + ((size_t)b * L_ + r0) * D_;

    __shared__ float sQ[TQ * QSTRIDE];
    __shared__ float sS2[TQ * SSTRIDE];

    const int t = threadIdx.x;

    for (int i = t; i < TQ * DC; i += NTF) {
        const int row = i / DC, c = i % DC;
        ((float4*)(sQ + row * QSTRIDE))[c] = ((const float4*)Qg)[i];
    }
    __syncthreads();

    {
        const int q  = t & (TQ - 1);
        const int kgI = t >> 3;
        float acc[32];
        #pragma unroll
        for (int w2 = 0; w2 < 32; ++w2) acc[w2] = 0.f;
        const float4* __restrict__ Qrow = (const float4*)(sQ + q * QSTRIDE);
        const float4* __restrict__ K4   = (const float4*)Kg;
        for (int c = 0; c < DC; ++c) {
            const float4 qv = Qrow[c];
            #pragma unroll
            for (int w2 = 0; w2 < 32; ++w2) {
                const float4 kv = K4[(kgI + 32 * w2) * DC + c];
                acc[w2] = fmaf(qv.x, kv.x, acc[w2]);
                acc[w2] = fmaf(qv.y, kv.y, acc[w2]);
                acc[w2] = fmaf(qv.z, kv.z, acc[w2]);
                acc[w2] = fmaf(qv.w, kv.w, acc[w2]);
            }
        }
        #pragma unroll
        for (int w2 = 0; w2 < 32; ++w2) sS2[q * SSTRIDE + kgI + 32 * w2] = acc[w2];
    }
    __syncthreads();

    {
        const int q = t >> 5;
        const int l = t & 31;
        float* __restrict__ row = sS2 + q * SSTRIDE;
        float mx = -3.0e38f;
        for (int k = l; k < L_; k += 32) mx = fmaxf(mx, row[k]);
        #pragma unroll
        for (int off = 16; off > 0; off >>= 1) mx = fmaxf(mx, __shfl_xor(mx, off));
        float se = 0.f;
        for (int k = l; k < L_; k += 32) {
            const float e = __expf(row[k] - mx);
            row[k] = e;
            se += e;
        }
        #pragma unroll
        for (int off = 16; off > 0; off >>= 1) se += __shfl_xor(se, off);
        const float inv = 1.0f / se;
        for (int k = l; k < L_; k += 32) row[k] *= inv;
    }
    __syncthreads();

    {
        const int q  = t & (TQ - 1);
        const int cg = t >> 3;
        float4 acc[6];
        #pragma unroll
        for (int r = 0; r < 6; ++r) acc[r] = make_float4(0.f, 0.f, 0.f, 0.f);
        const float* __restrict__ P   = sS2 + q * SSTRIDE;
        const float4* __restrict__ V4 = (const float4*)Kg;
        for (int k = 0; k < L_; ++k) {
            const float p = P[k];
            if (p > 1e-8f) {
                const float4* __restrict__ Vrow = V4 + (size_t)k * DC;
                #pragma unroll
                for (int r = 0; r < 6; ++r) {
                    const float4 v = Vrow[cg + 32 * r];
                    acc[r].x = fmaf(p, v.x, acc[r].x);
                    acc[r].y = fmaf(p, v.y, acc[r].y);
                    acc[r].z = fmaf(p, v.z, acc[r].z);
                    acc[r].w = fmaf(p, v.w, acc[r].w);
                }
            }
        }
        float4* __restrict__ O4 = (float4*)(Og + q * D_);
        #pragma unroll
        for (int r = 0; r < 6; ++r) O4[cg + 32 * r] = acc[r];
    }
}

extern "C" void kernel_launch(void* const* d_in, const int* in_sizes, int n_in,
                              void* d_out, int out_size, void* d_ws, size_t ws_size,
                              hipStream_t stream) {
    const float* X1 = (const float*)d_in[0];
    const float* X2 = (const float*)d_in[1];
    float* out = (float*)d_out;

    const size_t attBytes = (size_t)B_ * L_ * L_ * sizeof(float);     // 134,217,728
    const size_t hBytes   = (size_t)B_ * L_ * D_ * sizeof(_Float16);  // 50,331,648
    const size_t maxBytes = 2 * (size_t)B_ * L_ * sizeof(unsigned);   // 262,144
    const size_t needFull = attBytes + 4 * hBytes + maxBytes;         // ~320.25 MiB
    const size_t needMid  = attBytes + 2 * hBytes + maxBytes;         // ~224.25 MiB

    const int smpvLds = 64 * PSTR * 2 + 4096 + 256;                   // 136,448 B

    if (ws_size >= needFull) {
        float*    attW    = (float*)d_ws;
        _Float16* X1h     = (_Float16*)((char*)d_ws + attBytes);
        _Float16* X1l     = (_Float16*)((char*)d_ws + attBytes + 1 * hBytes);
        _Float16* X2h     = (_Float16*)((char*)d_ws + attBytes + 2 * hBytes);
        _Float16* X2l     = (_Float16*)((char*)d_ws + attBytes + 3 * hBytes);
        unsigned* rowMaxK = (unsigned*)((char*)d_ws + attBytes + 4 * hBytes);
        unsigned* colMaxK = rowMaxK + (size_t)B_ * L_;
        // transposed hi arrays overwrite the (then dead) lo arrays
        _Float16* X1hT = X1l;
        _Float16* X2hT = X2l;

        convert_rm<<<dim3(12288, 2), dim3(256), 0, stream>>>(
            X1, X2, X1h, X1l, X2h, X2l, rowMaxK, colMaxK);
        gemm_att_h<<<dim3(2048), dim3(256), 0, stream>>>(
            X1h, X1l, X2h, X2l, attW, rowMaxK, colMaxK);
        convert_T<<<dim3(L_ / 64, D_ / 64, B_ * 2), dim3(256), 0, stream>>>(
            X1h, X2h, X1hT, X2hT);
        smpv3<<<dim3(1024), dim3(1024), smpvLds, stream>>>(
            attW, X1hT, X2hT, rowMaxK, colMaxK, out);
    } else if (ws_size >= needMid) {
        float*    attW    = (float*)d_ws;
        _Float16* X1hT    = (_Float16*)((char*)d_ws + attBytes);
        _Float16* X2hT    = (_Float16*)((char*)d_ws + attBytes + hBytes);
        unsigned* rowMaxK = (unsigned*)((char*)d_ws + attBytes + 2 * hBytes);
        unsigned* colMaxK = rowMaxK + (size_t)B_ * L_;

        convert_kernel<<<dim3(L_ / 64, D_ / 64, B_ * 2), dim3(256), 0, stream>>>(
            X1, X2, X1hT, X2hT, rowMaxK, colMaxK);
        gemm_att<<<dim3(L_ / 128, L_ / 128, B_), dim3(256), 0, stream>>>(
            X1, X2, attW, rowMaxK, colMaxK);
        smpv3<<<dim3(1024), dim3(1024), smpvLds, stream>>>(
            attW, X1hT, X2hT, rowMaxK, colMaxK, out);
    } else {
        attn_fused_fallback<<<dim3(L_ / TQ, B_, 2), dim3(NTF), 0, stream>>>(X1, X2, out);
    }
}